// Round 6
// baseline (426.336 us; speedup 1.0000x reference)
//
#include <hip/hip_runtime.h>
#include <hip/hip_bf16.h>
#include <math.h>

// Problem constants: x [8, 96, 256, 256] fp32, window 16x16 -> 2048 windows.
#define NWIN 2048

typedef __bf16 v8bf __attribute__((ext_vector_type(8)));
typedef float  v4f  __attribute__((ext_vector_type(4)));

// Kernel 1 (batched): block handles 16 windows (one batch-row of windows),
// staging w_real/car_w1/car_w2 ONCE per block.
__global__ __launch_bounds__(128) void se_alpha_kernel(
    const float* __restrict__ x,
    const float* __restrict__ w_real, const float* __restrict__ b_real,
    const float* __restrict__ car_w1, const float* __restrict__ car_b1,
    const float* __restrict__ car_w2, const float* __restrict__ car_b2,
    const float* __restrict__ b_imag,
    const float* __restrict__ cai_w1, const float* __restrict__ cai_b1,
    const float* __restrict__ cai_w2, const float* __restrict__ cai_b2,
    float* __restrict__ alpha, float* __restrict__ beta)
{
    __shared__ float wr_s[96 * 97];   // +1 pad
    __shared__ float w1_s[32 * 97];   // car_w1 [32][96]
    __shared__ float w2_s[96 * 33];   // car_w2 [96][32]
    __shared__ float x0_s[96 * 17];   // corner pixel per chan x 16 windows
    __shared__ float pr_s[16 * 97];   // pooled [win][o]
    __shared__ float h1_s[16 * 33];   // hidden [win][j]
    const int t = threadIdx.x;
    const int blkid = blockIdx.x;

    if (blkid < 128) {
        const int b = blkid >> 4, wh = blkid & 15;
        for (int idx = t; idx < 96 * 96; idx += 128) {
            int o = idx / 96, c = idx - o * 96;
            wr_s[o * 97 + c] = w_real[idx];
        }
        for (int idx = t; idx < 32 * 96; idx += 128) {
            int j = idx / 96, c = idx - j * 96;
            w1_s[j * 97 + c] = car_w1[idx];
        }
        for (int idx = t; idx < 96 * 32; idx += 128) {
            int o = idx >> 5, j = idx & 31;
            w2_s[o * 33 + j] = car_w2[idx];
        }
        for (int idx = t; idx < 96 * 16; idx += 128) {
            int c = idx >> 4, w = idx & 15;
            x0_s[c * 17 + w] = x[(((size_t)(b * 96 + c)) * 256 + wh * 16) * 256 + w * 16];
        }
        __syncthreads();
        #pragma unroll
        for (int i = 0; i < 12; ++i) {
            int p = t + i * 128;            // 96*16 = 1536
            int o = p >> 4, w = p & 15;
            float acc = 0.f;
            #pragma unroll 4
            for (int c = 0; c < 96; ++c) acc += wr_s[o * 97 + c] * x0_s[c * 17 + w];
            pr_s[w * 97 + o] = acc * (1.0f / 16.0f) + b_real[o];
        }
        __syncthreads();
        #pragma unroll
        for (int i = 0; i < 4; ++i) {
            int p = t + i * 128;            // 32*16 = 512
            int j = p >> 4, w = p & 15;
            float acc = car_b1[j];
            #pragma unroll 4
            for (int o = 0; o < 96; ++o) acc += w1_s[j * 97 + o] * pr_s[w * 97 + o];
            h1_s[w * 33 + j] = fmaxf(acc, 0.f);
        }
        __syncthreads();
        #pragma unroll
        for (int i = 0; i < 12; ++i) {
            int p = t + i * 128;            // 96*16 = 1536
            int o = p >> 4, w = p & 15;
            float acc = car_b2[o];
            #pragma unroll
            for (int j = 0; j < 32; ++j) acc += w2_s[o * 33 + j] * h1_s[w * 33 + j];
            int n = (blkid << 4) | w;
            alpha[(size_t)n * 96 + o] = 1.f + 1.f / (1.f + __expf(-acc));
        }
    } else {
        if (t < 32) {
            float acc = cai_b1[t];
            for (int o = 0; o < 96; ++o) acc += cai_w1[t * 96 + o] * b_imag[o];
            h1_s[t] = fmaxf(acc, 0.f);
        }
        __syncthreads();
        if (t < 96) {
            float acc = cai_b2[t];
            for (int j = 0; j < 32; ++j) acc += cai_w2[t * 32 + j] * h1_s[j];
            beta[t] = 1.f + 1.f / (1.f + __expf(-acc));
        }
    }
}

// Kernel 2 (2 blocks/CU): out[p,o] = alpha[n,o]*U[p,o] + V[p,o]
//   (+16*alpha*b_r at window pixel (0,0))
//   U = (Wr/2)*(x_p + x_flip(p)),  V = (beta.*Wi/2)*(x_p - x_flip(p))
// Round-5 analysis: 1 block/CU barrier-convoy left every pipe <35% busy
// (12.2K cyc/phase vs ~4K of work). This round: 512-thread blocks (8 waves,
// 4 windows = one column-quarter), LDS 74.2KB -> 2 blocks/CU so one block's
// phase bubbles are absorbed by the other. Depth-1 DMA double-buffer with
// counted vmcnt (k0-top vmcnt(6) = 2 loads + 6 stores ledger; k1/k2 tops
// drain own loads, co-resident block covers). Reads stay 256B-contiguous;
// chan-quad XOR pre-swizzle of global col keeps frag reads <=2-way banked.
__global__ __launch_bounds__(512, 4) void wfca_main_kernel(
    const float* __restrict__ x,
    const float* __restrict__ w_real, const float* __restrict__ w_imag,
    const float* __restrict__ b_real,
    const float* __restrict__ alpha, const float* __restrict__ beta,
    float* __restrict__ out)
{
    __shared__ __bf16 wr_s[96 * 104];        // 0.5*Wr
    __shared__ __bf16 wi_s[96 * 104];        // 0.5*beta[o]*Wi
    __shared__ float  xf[2][32 * 128];       // fp32 x: [buf][chan][2 rows x 64 cols]
    __shared__ float  alpha_s[384];          // 4 windows x 96

    const int t    = threadIdx.x;
    const int blk  = blockIdx.x;             // 512 = b(3) | wh(4) | cq(2)
    const int b    = blk >> 6;               // batch
    const int wh   = (blk >> 2) & 15;        // window row
    const int cq   = blk & 3;                // column quarter (4 windows)

    const int lane = t & 63;
    const int l16  = lane & 15;
    const int quad = lane >> 4;
    const int wv   = t >> 6;                 // 0..7
    const int r2m  = wv >> 2;                // wave's row within pair (0=lo,1=hi)
    const int wm   = wv & 3;                 // wave's window within quarter

    // fragment cols: de-swizzle matches the chan-quad source pre-swizzle below
    const int pxq = (wm * 16 + l16) ^ (quad << 4);
    const int pfq = (wm * 16 + ((16 - l16) & 15)) ^ (quad << 4);

    // DMA: wave loads 4 chans (2 instr x 2 chans); per chan 2 rows x 64 cols
    // (256B contiguous runs). Global col pre-swizzled by chan quad so LDS is
    // linear (m173 pattern) and frag reads are <=2-way banked.
    auto issue = [&](int rp_, int k_, int buf_) {
        const int hl = rp_;
        const int hh = (rp_ == 0) ? 8 : 16 - rp_;
        #pragma unroll
        for (int u = 0; u < 2; ++u) {
            const int c    = 4 * wv + 2 * u + (lane >> 5);   // chunk-local chan
            const int row  = ((lane & 31) >> 4) ? hh : hl;
            const int colg = (4 * (lane & 15)) ^ (((c >> 3) & 3) << 4);
            const float* g = x + (((size_t)(b * 96 + k_ * 32 + c)) << 16)
                           + (size_t)(wh * 16 + row) * 256 + cq * 64 + colg;
            float* l = &xf[buf_][(4 * wv + 2 * u) * 128];    // wave-uniform base
            __builtin_amdgcn_global_load_lds(
                (const __attribute__((address_space(1))) float*)g,
                (__attribute__((address_space(3))) float*)l, 16, 0, 0);
        }
    };

    // ---- prologue: weights+alpha+b_real via normal loads, full sync, prime ----
    #pragma unroll
    for (int gph = 0; gph < 2; ++gph) {      // two batches of 9 to cap live regs
        float wrv[9], wiv[9], btv[9];
        #pragma unroll
        for (int r = 0; r < 9; ++r) {
            int idx = t + (gph * 9 + r) * 512;   // 18*512 = 9216 = 96*96 exact
            wrv[r] = w_real[idx];
            wiv[r] = w_imag[idx];
            btv[r] = beta[idx / 96];
        }
        #pragma unroll
        for (int r = 0; r < 9; ++r) {
            int idx = t + (gph * 9 + r) * 512;
            int o = idx / 96, c = idx - o * 96;
            wr_s[o * 104 + c] = (__bf16)(0.5f * wrv[r]);
            wi_s[o * 104 + c] = (__bf16)(0.5f * btv[r] * wiv[r]);
        }
    }
    if (t < 384) {
        int w = t / 96, o = t - w * 96;
        alpha_s[t] = alpha[(size_t)(b * 256 + wh * 16 + cq * 4 + w) * 96 + o];
    }
    float brv[6];
    #pragma unroll
    for (int n = 0; n < 6; ++n) brv[n] = b_real[n * 16 + l16];
    __syncthreads();                          // drains all vmcnt: clean ledger

    issue(0, 0, 0);

    for (int rp = 0; rp < 8; ++rp) {
        const int h_lo   = rp;
        const int h_hi   = (rp == 0) ? 8 : 16 - rp;
        const int h_out  = r2m ? h_hi : h_lo;
        const int flipr2 = (rp == 0) ? r2m : 1 - r2m;

        float af[6];
        v4f acc[6];
        #pragma unroll
        for (int n = 0; n < 6; ++n) {
            af[n]  = alpha_s[wm * 96 + n * 16 + l16];
            acc[n] = v4f{0.f, 0.f, 0.f, 0.f};
        }
        #pragma unroll
        for (int k = 0; k < 3; ++k) {
            const int p = rp * 3 + k;
            // counted wait: per-wave stream = 2 loads/phase + 6 stores/row-pair.
            // k0 (rp>0): outstanding = [2 loads chunk p (old), 6 stores (new)]
            //            -> vmcnt(6) retires the loads, keeps stores in flight.
            // otherwise: only own 2 loads outstanding -> vmcnt(0) (issued a
            //            full phase ago; co-resident block hides any tail).
            if (k == 0 && rp > 0) asm volatile("s_waitcnt vmcnt(6)" ::: "memory");
            else                  asm volatile("s_waitcnt vmcnt(0)" ::: "memory");
            __builtin_amdgcn_s_barrier();     // chunk p landed for all waves
            __builtin_amdgcn_sched_barrier(0);

            // issue next chunk into the other buffer (freed by barrier above)
            if (p < 23) {
                int pn = p + 1;
                issue(pn / 3, pn % 3, pn & 1);
            }

            // fragments from fp32 LDS, cvt to bf16
            const float* xk = xf[p & 1];
            float fxv[8], ffv[8];
            #pragma unroll
            for (int j = 0; j < 8; ++j) {
                fxv[j] = xk[(quad * 8 + j) * 128 + r2m * 64 + pxq];
                ffv[j] = xk[(quad * 8 + j) * 128 + flipr2 * 64 + pfq];
            }
            v8bf a_x, a_f, a_fn;
            #pragma unroll
            for (int j = 0; j < 8; ++j) {
                a_x[j]  = (__bf16)fxv[j];
                a_f[j]  = (__bf16)ffv[j];
                a_fn[j] = (__bf16)(-ffv[j]);
            }
            const int c0 = k * 32;
            #pragma unroll
            for (int n = 0; n < 6; ++n) {
                v8bf bwr = *(const v8bf*)&wr_s[(n * 16 + l16) * 104 + c0 + quad * 8];
                v8bf bwi = *(const v8bf*)&wi_s[(n * 16 + l16) * 104 + c0 + quad * 8];
                acc[n] = __builtin_amdgcn_mfma_f32_16x16x32_bf16(a_x,  bwi, acc[n], 0, 0, 0);
                acc[n] = __builtin_amdgcn_mfma_f32_16x16x32_bf16(a_fn, bwi, acc[n], 0, 0, 0);
                v4f utmp = __builtin_amdgcn_mfma_f32_16x16x32_bf16(
                               a_x, bwr, v4f{0.f, 0.f, 0.f, 0.f}, 0, 0, 0);
                utmp = __builtin_amdgcn_mfma_f32_16x16x32_bf16(a_f, bwr, utmp, 0, 0, 0);
                #pragma unroll
                for (int r = 0; r < 4; ++r) acc[n][r] += af[n] * utmp[r];
            }
        }

        // epilogue: C/D col=l16 (out-chan), row=quad*4+r (= pixel col in window)
        {
            #pragma unroll
            for (int n = 0; n < 6; ++n) {
                const int o = n * 16 + l16;
                v4f v = acc[n];
                if (h_out == 0 && quad == 0) {
                    // bias delta at window pixel (0,0): IFFT of const b_r = 16*b_r
                    v[0] += 16.f * af[n] * brv[n];
                }
                size_t idx = (((size_t)(b * 96 + o)) * 256 + wh * 16 + h_out) * 256
                             + cq * 64 + wm * 16 + quad * 4;
                *(v4f*)(out + idx) = v;
            }
        }
    }
}

extern "C" void kernel_launch(void* const* d_in, const int* in_sizes, int n_in,
                              void* d_out, int out_size, void* d_ws, size_t ws_size,
                              hipStream_t stream) {
    const float* x      = (const float*)d_in[0];
    const float* w_real = (const float*)d_in[1];
    const float* b_real = (const float*)d_in[2];
    const float* w_imag = (const float*)d_in[3];
    const float* b_imag = (const float*)d_in[4];
    const float* car_w1 = (const float*)d_in[5];
    const float* car_b1 = (const float*)d_in[6];
    const float* car_w2 = (const float*)d_in[7];
    const float* car_b2 = (const float*)d_in[8];
    const float* cai_w1 = (const float*)d_in[9];
    const float* cai_b1 = (const float*)d_in[10];
    const float* cai_w2 = (const float*)d_in[11];
    const float* cai_b2 = (const float*)d_in[12];
    float* out = (float*)d_out;

    float* alpha = (float*)d_ws;            // [2048*96]
    float* beta  = alpha + NWIN * 96;       // [96]

    se_alpha_kernel<<<129, 128, 0, stream>>>(
        x, w_real, b_real, car_w1, car_b1, car_w2, car_b2,
        b_imag, cai_w1, cai_b1, cai_w2, cai_b2, alpha, beta);

    wfca_main_kernel<<<512, 512, 0, stream>>>(
        x, w_real, w_imag, b_real, alpha, beta, out);
}